// Round 1
// baseline (556.738 us; speedup 1.0000x reference)
//
#include <hip/hip_runtime.h>
#include <math.h>

#define HF   14
#define DIM  16384
#define NTH  512

// -------- gate matrix precompute: 252 gates x 8 floats --------------------
// Rot(phi,theta,omega) = RZ(omega) RY(theta) RZ(phi)
// U00 = e^{-i(phi+om)/2} c ; U01 = -e^{+i(phi-om)/2} s
// U10 = e^{-i(phi-om)/2} s ; U11 = e^{+i(phi+om)/2} c
__global__ void k_gates(const float* __restrict__ w1, float* __restrict__ g)
{
    int gi = blockIdx.x * blockDim.x + threadIdx.x;
    if (gi >= 252) return;
    float phi = w1[gi * 3 + 0];
    float th  = w1[gi * 3 + 1];
    float om  = w1[gi * 3 + 2];
    float s, c, sa, ca, sb, cb;
    sincosf(0.5f * th, &s, &c);
    sincosf(0.5f * (phi + om), &sa, &ca);
    sincosf(0.5f * (phi - om), &sb, &cb);
    float* o = g + gi * 8;
    o[0] =  c * ca;  o[1] = -c * sa;   // U00
    o[2] = -s * cb;  o[3] = -s * sb;   // U01
    o[4] =  s * cb;  o[5] = -s * sb;   // U10
    o[6] =  c * ca;  o[7] =  c * sa;   // U11
}

// -------- linear_down: xr[64][14] = x(64,784) @ w_down(14,784)^T + b ------
__global__ void k_down(const float* __restrict__ x, const float* __restrict__ wd,
                       const float* __restrict__ bd, float* __restrict__ xr)
{
    int row  = blockIdx.x;
    int wave = threadIdx.x >> 6;
    int lane = threadIdx.x & 63;
    const float* xrow = x + row * 784;
    for (int f = wave; f < HF; f += 4) {
        const float* wrow = wd + f * 784;
        float s = 0.f;
        for (int j = lane; j < 784; j += 64) s = fmaf(xrow[j], wrow[j], s);
        #pragma unroll
        for (int off = 32; off; off >>= 1) s += __shfl_xor(s, off);
        if (lane == 0) xr[row * HF + f] = s + bd[f];
    }
}

// -------- BatchNorm1d (training-mode batch stats over 64 rows) ------------
__global__ void k_bn(const float* __restrict__ xr, const float* __restrict__ bw,
                     const float* __restrict__ bb, float* __restrict__ out)
{
    int t = threadIdx.x;   // 64 threads = 1 wave = 64 rows
    for (int f = 0; f < HF; ++f) {
        float v = xr[t * HF + f];
        float s = v;
        #pragma unroll
        for (int off = 32; off; off >>= 1) s += __shfl_xor(s, off);
        float mu = s * (1.f / 64.f);
        float dv = v - mu;
        float q = dv * dv;
        #pragma unroll
        for (int off = 32; off; off >>= 1) q += __shfl_xor(q, off);
        float var = q * (1.f / 64.f);
        out[t * HF + f] = dv * (1.f / sqrtf(var + 1e-5f)) * bw[f] + bb[f];
    }
}

// -------- statevector circuit ---------------------------------------------
// LDS swizzle: bank-conflict-free for every pass group (verified 2 lanes/bank)
__device__ __forceinline__ int swz(int d) { return d ^ ((d >> 3) & 63); }

// One fused pass: apply the layer's gates on wires with state-bits [LO, LO+K)
// (wire q <-> bit 13-q). diagMode: bit0 = CZ(range czr) pending, bit1 = RZ pending.
template<int LO, int K>
__device__ __forceinline__ void gate_pass(float* __restrict__ sre, float* __restrict__ sim,
                                          const float* __restrict__ GL,
                                          int diagMode, int czr,
                                          const float* __restrict__ xv, float Sx, int tid)
{
    constexpr int N     = 1 << K;
    constexpr int OUTER = DIM >> K;
    #pragma unroll
    for (int it = 0; it < OUTER / NTH; ++it) {
        int o    = tid + it * NTH;
        int low  = o & ((1 << LO) - 1);
        int high = o >> LO;
        int base = (high << (LO + K)) | low;
        float vr[N], vi[N];

        float baseAng = 0.f;
        if (diagMode & 2) {
            baseAng = -0.5f * Sx;
            #pragma unroll
            for (int p = 0; p < HF; ++p) {
                if (p < LO || p >= LO + K)
                    if (base & (1 << p)) baseAng += xv[13 - p];
            }
        }
        #pragma unroll
        for (int r = 0; r < N; ++r) {
            int d = base | (r << LO);
            int a = swz(d);
            float re = sre[a], im = sim[a];
            if (diagMode & 1) {   // CZ ring, range czr: sign = (-1)^{popc(d & rot14(d,czr))}
                int rot = ((d >> czr) | (d << (14 - czr))) & (DIM - 1);
                if (__popc(d & rot) & 1) { re = -re; im = -im; }
            }
            if (diagMode & 2) {   // RZ re-upload phase e^{i ang}
                float ang = baseAng;
                #pragma unroll
                for (int j = 0; j < K; ++j)
                    if (r & (1 << j)) ang += xv[13 - (LO + j)];
                float sn, cs;
                sincosf(ang, &sn, &cs);
                float nr = re * cs - im * sn;
                float ni = re * sn + im * cs;
                re = nr; im = ni;
            }
            vr[r] = re; vi[r] = im;
        }
        // gates on register-bit j (wire 13-(LO+j)), any order (commuting wires)
        #pragma unroll
        for (int j = 0; j < K; ++j) {
            const float* G = GL + 8 * (13 - (LO + j));
            float g0 = G[0], g1 = G[1], g2 = G[2], g3 = G[3];
            float g4 = G[4], g5 = G[5], g6 = G[6], g7 = G[7];
            #pragma unroll
            for (int m = 0; m < N / 2; ++m) {
                int r0 = ((m >> j) << (j + 1)) | (m & ((1 << j) - 1));
                int r1 = r0 | (1 << j);
                float a0r = vr[r0], a0i = vi[r0], a1r = vr[r1], a1i = vi[r1];
                vr[r0] = g0 * a0r - g1 * a0i + g2 * a1r - g3 * a1i;
                vi[r0] = g0 * a0i + g1 * a0r + g2 * a1i + g3 * a1r;
                vr[r1] = g4 * a0r - g5 * a0i + g6 * a1r - g7 * a1i;
                vi[r1] = g4 * a0i + g5 * a0r + g6 * a1i + g7 * a1r;
            }
        }
        #pragma unroll
        for (int r = 0; r < N; ++r) {
            int a = swz(base | (r << LO));
            sre[a] = vr[r]; sim[a] = vi[r];
        }
    }
    __syncthreads();
}

__global__ __launch_bounds__(NTH)
void k_circuit(const float* __restrict__ xrin, const float* __restrict__ gstep,
               float* __restrict__ xrout)
{
    __shared__ float sre[DIM];
    __shared__ float sim[DIM];
    int row = blockIdx.x;
    int tid = threadIdx.x;

    float xv[HF];
    float Sx = 0.f;
    #pragma unroll
    for (int j = 0; j < HF; ++j) { xv[j] = xrin[row * HF + j]; Sx += xv[j]; }

    for (int a = tid; a < DIM; a += NTH) { sre[a] = 0.f; sim[a] = 0.f; }
    __syncthreads();
    if (tid == 0) sre[0] = 1.f;            // swz(0) == 0
    __syncthreads();

    for (int i = 0; i < 3; ++i) {
        for (int l = 0; l < 3; ++l) {
            const float* GL = gstep + (i * 3 + l) * 112;   // 14 gates * 8 floats
            int diagMode, czr;
            if (l == 0) { diagMode = (i > 0) ? 3 : 2; czr = 3; }   // RZ (+ prev CZ range 3)
            else        { diagMode = 1; czr = l; }                 // CZ range l
            gate_pass<10, 4>(sre, sim, GL, diagMode, czr, xv, Sx, tid);
            gate_pass< 6, 4>(sre, sim, GL, 0, 0, xv, Sx, tid);
            gate_pass< 3, 3>(sre, sim, GL, 0, 0, xv, Sx, tid);
            gate_pass< 0, 3>(sre, sim, GL, 0, 0, xv, Sx, tid);
        }
    }
    // trailing CZ (range 3) dropped: |amp|^2 invariant under sign diagonal.

    // expvals <Z_j> = sum_d p_d * (1 - 2*bit_{13-j}(d))
    float tot = 0.f;
    float accv[HF];
    #pragma unroll
    for (int j = 0; j < HF; ++j) accv[j] = 0.f;
    for (int o = tid; o < DIM; o += NTH) {
        int a = swz(o);
        float re = sre[a], im = sim[a];
        float p = fmaf(re, re, im * im);
        tot += p;
        #pragma unroll
        for (int j = 0; j < HF; ++j)
            if (o & (1 << (13 - j))) accv[j] += p;
    }
    #pragma unroll
    for (int off = 32; off; off >>= 1) {
        tot += __shfl_xor(tot, off);
        #pragma unroll
        for (int j = 0; j < HF; ++j) accv[j] += __shfl_xor(accv[j], off);
    }
    __syncthreads();               // all state reads done before scratch reuse
    int wave = tid >> 6, lane = tid & 63;
    if (lane == 0) {
        #pragma unroll
        for (int j = 0; j < HF; ++j) sre[wave * 16 + 1 + j] = accv[j];
        sre[wave * 16] = tot;
    }
    __syncthreads();
    if (tid < HF) {
        float t2 = 0.f, a3 = 0.f;
        #pragma unroll
        for (int w = 0; w < NTH / 64; ++w) {
            t2 += sre[w * 16];
            a3 += sre[w * 16 + 1 + tid];
        }
        xrout[row * HF + tid] = t2 - 2.f * a3;
    }
}

// -------- linear_up: out[64][784] = xr @ w_up(784,14)^T + b_up ------------
__global__ void k_up(const float* __restrict__ xr, const float* __restrict__ wu,
                     const float* __restrict__ bu, float* __restrict__ out)
{
    int b = blockIdx.x;
    float xvv[HF];
    #pragma unroll
    for (int f = 0; f < HF; ++f) xvv[f] = xr[b * HF + f];
    for (int j = threadIdx.x; j < 784; j += 256) {
        float s = bu[j];
        #pragma unroll
        for (int f = 0; f < HF; ++f) s = fmaf(xvv[f], wu[j * HF + f], s);
        out[b * 784 + j] = s;
    }
}

extern "C" void kernel_launch(void* const* d_in, const int* in_sizes, int n_in,
                              void* d_out, int out_size, void* d_ws, size_t ws_size,
                              hipStream_t stream)
{
    const float* x  = (const float*)d_in[0];
    const float* wd = (const float*)d_in[1];
    const float* bd = (const float*)d_in[2];
    const float* bw = (const float*)d_in[3];
    const float* bb = (const float*)d_in[4];
    const float* w1 = (const float*)d_in[5];
    const float* wu = (const float*)d_in[6];
    const float* bu = (const float*)d_in[7];
    float* out = (float*)d_out;

    float* ws    = (float*)d_ws;
    float* gates = ws;          // 252*8 = 2016 floats
    float* xr    = ws + 2048;   // 64*14 = 896 floats
    float* xrbn  = ws + 3072;   // 896 floats

    hipLaunchKernelGGL(k_gates, dim3(1),  dim3(256), 0, stream, w1, gates);
    hipLaunchKernelGGL(k_down,  dim3(64), dim3(256), 0, stream, x, wd, bd, xr);
    for (int n = 0; n < 2; ++n) {
        hipLaunchKernelGGL(k_bn,      dim3(1),  dim3(64),  0, stream, xr, bw, bb, xrbn);
        hipLaunchKernelGGL(k_circuit, dim3(64), dim3(NTH), 0, stream, xrbn,
                           gates + n * 126 * 8, xr);
    }
    hipLaunchKernelGGL(k_up, dim3(64), dim3(256), 0, stream, xr, wu, bu, out);
}

// Round 2
// 227.636 us; speedup vs baseline: 2.4457x; 2.4457x over previous
//
#include <hip/hip_runtime.h>
#include <math.h>

#define HF  14
#define DIM 16384
#define NTH 512
#define PRE_STRIDE 384
#define AL_OFF 252

// ---- precompute: per step n: ry[9][14][2]={cos(th/2),sin(th/2)}, alpha[8][14]=w+phi_next
__global__ void k_pre(const float* __restrict__ w1, float* __restrict__ pre)
{
    int tid = threadIdx.x;
    if (tid < 252) {                       // (n, LL, q) -> (c,s) of theta
        int n = tid / 126, r = tid % 126, LL = r / 14, q = r % 14;
        float th = w1[n*378 + LL*42 + q*3 + 1];
        float s, c;
        sincosf(0.5f * th, &s, &c);
        float* o = pre + n*PRE_STRIDE + (LL*14 + q)*2;
        o[0] = c; o[1] = s;
    } else if (tid >= 256 && tid < 480) {  // alpha[k][q] = omega_LL=k + phi_LL=k+1
        int idx = tid - 256, n = idx / 112, r2 = idx % 112, k = r2 / 14, q = r2 % 14;
        pre[n*PRE_STRIDE + AL_OFF + k*14 + q] =
            w1[n*378 + k*42 + q*3 + 2] + w1[n*378 + (k+1)*42 + q*3 + 0];
    }
}

// ---- linear_down: xr[64][14]
__global__ void k_down(const float* __restrict__ x, const float* __restrict__ wd,
                       const float* __restrict__ bd, float* __restrict__ xr)
{
    int row  = blockIdx.x;
    int wave = threadIdx.x >> 6;
    int lane = threadIdx.x & 63;
    const float* xrow = x + row * 784;
    for (int f = wave; f < HF; f += 4) {
        const float* wrow = wd + f * 784;
        float s = 0.f;
        for (int j = lane; j < 784; j += 64) s = fmaf(xrow[j], wrow[j], s);
        #pragma unroll
        for (int off = 32; off; off >>= 1) s += __shfl_xor(s, off);
        if (lane == 0) xr[row * HF + f] = s + bd[f];
    }
}

// ---- BatchNorm1d (batch stats over 64 rows)
__global__ void k_bn(const float* __restrict__ xr, const float* __restrict__ bw,
                     const float* __restrict__ bb, float* __restrict__ out)
{
    int t = threadIdx.x;   // 64 threads = 64 rows
    for (int f = 0; f < HF; ++f) {
        float v = xr[t * HF + f];
        float s = v;
        #pragma unroll
        for (int off = 32; off; off >>= 1) s += __shfl_xor(s, off);
        float mu = s * (1.f / 64.f);
        float dv = v - mu;
        float q = dv * dv;
        #pragma unroll
        for (int off = 32; off; off >>= 1) q += __shfl_xor(q, off);
        float var = q * (1.f / 64.f);
        out[t * HF + f] = dv * (1.f / sqrtf(var + 1e-5f)) * bw[f] + bb[f];
    }
}

// ---- statevector circuit, register-resident, rotate-by-5 window schedule ----
// Pass (k,m): window start B=(k+5m)%14; reg bit j <-> amp bit (B+j)%14;
// thread bit kk <-> amp bit (B+5+kk)%14. Diagonal Delta^k applied at m==0.
__global__ __launch_bounds__(NTH)
void k_circuit(const float* __restrict__ xrin, const float* __restrict__ pre,
               float* __restrict__ xrout)
{
    __shared__ __align__(16) float2 S[DIM];   // 128 KB transpose staging
    const float* ry    = pre;
    const float* alpha = pre + AL_OFF;
    int row = blockIdx.x, T = threadIdx.x;

    float vr[32], vi[32];

    // init = product state after RY layer LL=0 (window B=0 mapping)
    {
        float A = 1.f;
        #pragma unroll
        for (int kk = 0; kk < 9; ++kk) {
            int wire = 8 - kk;                       // amp bit 5+kk -> wire 13-(5+kk)
            float c = ry[wire*2], s = ry[wire*2 + 1];
            A *= ((T >> kk) & 1) ? s : c;
        }
        #pragma unroll
        for (int r = 0; r < 32; ++r) {
            float p = A;
            #pragma unroll
            for (int j = 0; j < 5; ++j) {
                int wire = 13 - j;                   // amp bit j -> wire 13-j
                p *= ((r >> j) & 1) ? ry[wire*2 + 1] : ry[wire*2];
            }
            vr[r] = p; vi[r] = 0.f;
        }
    }

    #pragma unroll 1
    for (int k = 0; k < 8; ++k) {
        #pragma unroll 1
        for (int m = 0; m < 3; ++m) {
            int B = k + 5*m; if (B >= 14) B -= 14;

            if (m == 0) {   // Delta^k = Dphi_{k+1} * [RZup if k in {2,5}] * CZ((k%3)+1) * Domega_k
                int sh = B + 5; if (sh >= 14) sh -= 14;
                int dbase = ((T << sh) | (T >> (14 - sh))) & 16383;
                bool up = (k == 2) || (k == 5);
                float A = 0.f;
                #pragma unroll
                for (int bb = 0; bb < 14; ++bb) {
                    float a = alpha[k*14 + (13 - bb)];
                    if (up) a += xrin[row*HF + (13 - bb)];
                    A += ((dbase >> bb) & 1) ? a : 0.f;
                }
                float aj[5];
                #pragma unroll
                for (int j = 0; j < 5; ++j) {
                    int bit = B + j; if (bit >= 14) bit -= 14;
                    int q = 13 - bit;
                    float a = alpha[k*14 + q];
                    if (up) a += xrin[row*HF + q];
                    aj[j] = a;
                }
                int czr = (k % 3) + 1;
                #pragma unroll
                for (int r = 0; r < 32; ++r) {
                    unsigned sp = (((unsigned)r << B) | ((unsigned)r >> (14 - B))) & 16383u;
                    int d = dbase | (int)sp;
                    int rot = ((d >> czr) | (d << (14 - czr))) & 16383;
                    float pa = (float)(__popc(d & rot) & 1);
                    float ang = fmaf(pa, 3.14159265358979323f, A);
                    if (r & 1)  ang += aj[0];
                    if (r & 2)  ang += aj[1];
                    if (r & 4)  ang += aj[2];
                    if (r & 8)  ang += aj[3];
                    if (r & 16) ang += aj[4];
                    float sn, cs;
                    __sincosf(ang, &sn, &cs);
                    float nr = vr[r]*cs - vi[r]*sn;
                    float ni = vr[r]*sn + vi[r]*cs;
                    vr[r] = nr; vi[r] = ni;
                }
            }

            // RY gates on the 5 (4 when m==2) window bits
            {
                int LL = k + 1;
                #pragma unroll
                for (int j = 0; j < 5; ++j) {
                    if (j < 4 || m != 2) {
                        int bit = B + j; if (bit >= 14) bit -= 14;
                        int wire = 13 - bit;
                        float c = ry[(LL*14 + wire)*2 + 0];
                        float s = ry[(LL*14 + wire)*2 + 1];
                        #pragma unroll
                        for (int mm = 0; mm < 16; ++mm) {
                            int r0 = ((mm >> j) << (j+1)) | (mm & ((1 << j) - 1));
                            int r1 = r0 | (1 << j);
                            float a0r = vr[r0], a1r = vr[r1];
                            vr[r0] = c*a0r - s*a1r;
                            vr[r1] = s*a0r + c*a1r;
                            float a0i = vi[r0], a1i = vi[r1];
                            vi[r0] = c*a0i - s*a1i;
                            vi[r1] = s*a0i + c*a1i;
                        }
                    }
                }
            }

            // transpose (rotate window by +5); skip after the final pass
            if (!(k == 7 && m == 2)) {
                // store (t,r) -> float2 idx t'*32 + r', granule-XOR-swizzled:
                // t' = (t>>5)|(r<<4), r' = t&31, g' = g ^ (t'&7)
                int SB = ((T >> 5) << 5)
                       + (((((T & 31) >> 1) ^ ((T >> 5) & 7)) << 1) | (T & 1));
                float2* Shi = S + 8192;
                #pragma unroll
                for (int r = 0; r < 16; ++r)
                    S[SB + r*512] = make_float2(vr[r], vi[r]);
                #pragma unroll
                for (int r = 16; r < 32; ++r)
                    Shi[SB + (r-16)*512] = make_float2(vr[r], vi[r]);
                __syncthreads();
                const float4* S4 = (const float4*)S;
                int base4 = (T << 4) | (T & 7);      // swizzle folds into XOR
                #pragma unroll
                for (int kk = 0; kk < 16; ++kk) {
                    float4 f = S4[base4 ^ kk];
                    vr[2*kk]   = f.x; vi[2*kk]   = f.y;
                    vr[2*kk+1] = f.z; vi[2*kk+1] = f.w;
                }
                __syncthreads();
            }
        }
    }

    // probs + <Z>: final window B=3: reg j <-> bit 3+j; thread bits -> bits 8..13,0..2
    float tot = 0.f, Sj[5] = {0.f, 0.f, 0.f, 0.f, 0.f};
    #pragma unroll
    for (int r = 0; r < 32; ++r) {
        float p = fmaf(vr[r], vr[r], vi[r]*vi[r]);
        tot += p;
        if (r & 1)  Sj[0] += p;
        if (r & 2)  Sj[1] += p;
        if (r & 4)  Sj[2] += p;
        if (r & 8)  Sj[3] += p;
        if (r & 16) Sj[4] += p;
    }
    int dpr = ((T << 8) | (T >> 6)) & 16383;
    float acc[14];
    #pragma unroll
    for (int b = 0; b < 14; ++b) {
        if (b >= 3 && b < 8) acc[b] = Sj[b - 3];
        else                 acc[b] = ((dpr >> b) & 1) ? tot : 0.f;
    }
    #pragma unroll
    for (int off = 32; off; off >>= 1) {
        tot += __shfl_xor(tot, off);
        #pragma unroll
        for (int b = 0; b < 14; ++b) acc[b] += __shfl_xor(acc[b], off);
    }
    float* SP = (float*)S;
    int wv = T >> 6, ln = T & 63;
    if (ln == 0) {
        SP[wv*16] = tot;
        #pragma unroll
        for (int b = 0; b < 14; ++b) SP[wv*16 + 1 + b] = acc[b];
    }
    __syncthreads();
    if (T < HF) {
        float tt = 0.f, aa = 0.f;
        #pragma unroll
        for (int w = 0; w < 8; ++w) {
            tt += SP[w*16];
            aa += SP[w*16 + 1 + (13 - T)];
        }
        xrout[row*HF + T] = tt - 2.f*aa;
    }
}

// ---- linear_up: out[64][784]
__global__ void k_up(const float* __restrict__ xr, const float* __restrict__ wu,
                     const float* __restrict__ bu, float* __restrict__ out)
{
    int b = blockIdx.x;
    float xvv[HF];
    #pragma unroll
    for (int f = 0; f < HF; ++f) xvv[f] = xr[b * HF + f];
    for (int j = threadIdx.x; j < 784; j += 256) {
        float s = bu[j];
        #pragma unroll
        for (int f = 0; f < HF; ++f) s = fmaf(xvv[f], wu[j * HF + f], s);
        out[b * 784 + j] = s;
    }
}

extern "C" void kernel_launch(void* const* d_in, const int* in_sizes, int n_in,
                              void* d_out, int out_size, void* d_ws, size_t ws_size,
                              hipStream_t stream)
{
    const float* x  = (const float*)d_in[0];
    const float* wd = (const float*)d_in[1];
    const float* bd = (const float*)d_in[2];
    const float* bw = (const float*)d_in[3];
    const float* bb = (const float*)d_in[4];
    const float* w1 = (const float*)d_in[5];
    const float* wu = (const float*)d_in[6];
    const float* bu = (const float*)d_in[7];
    float* out = (float*)d_out;

    float* ws   = (float*)d_ws;
    float* pre  = ws;           // 2 * 384 floats
    float* xr   = ws + 1024;    // 64*14
    float* xrbn = ws + 2048;    // 64*14

    hipLaunchKernelGGL(k_pre,  dim3(1),  dim3(512), 0, stream, w1, pre);
    hipLaunchKernelGGL(k_down, dim3(64), dim3(256), 0, stream, x, wd, bd, xr);
    for (int n = 0; n < 2; ++n) {
        hipLaunchKernelGGL(k_bn,      dim3(1),  dim3(64),  0, stream, xr, bw, bb, xrbn);
        hipLaunchKernelGGL(k_circuit, dim3(64), dim3(NTH), 0, stream, xrbn,
                           pre + n * PRE_STRIDE, xr);
    }
    hipLaunchKernelGGL(k_up, dim3(64), dim3(256), 0, stream, xr, wu, bu, out);
}